// Round 5
// baseline (182.125 us; speedup 1.0000x reference)
//
#include <hip/hip_runtime.h>
#include <hip/hip_bf16.h>
#include <stdint.h>

typedef __attribute__((ext_vector_type(8))) short  short8;   // 8 bf16 (4 VGPR) MFMA A/B frag
typedef __attribute__((ext_vector_type(4))) short  short4v;
typedef __attribute__((ext_vector_type(4))) float  float4v;  // MFMA C/D frag

#define MFMA16(a, b, c) __builtin_amdgcn_mfma_f32_16x16x32_bf16((a), (b), (c), 0, 0, 0)

#define S_LEN  4096
#define NBATCH 4
#define EMB    1024
#define DD     64
#define NROWS  (NBATCH * S_LEN)  // 16384
#define SCL2   0.1803368801111204f  // (1/sqrt(64)) * log2(e), folded into Wq at wcvt

#define AS1 const __attribute__((address_space(1))) unsigned int*
#define AS3 __attribute__((address_space(3))) unsigned int*

static __device__ __forceinline__ short f2bf(float f) {
  uint32_t u = __float_as_uint(f);
  return (short)((u + 0x7FFFu + ((u >> 16) & 1u)) >> 16);
}
static __device__ __forceinline__ unsigned pk2(float a, float b) {
  union { __hip_bfloat162 h; unsigned u; } z;
  z.h = __float22bfloat162_rn(make_float2(a, b));
  return z.u;
}
static __device__ __forceinline__ short8 cvt8(float4v a, float4v b) {
  union { unsigned u[4]; short8 s; } z;
  z.u[0] = pk2(a[0], a[1]); z.u[1] = pk2(a[2], a[3]);
  z.u[2] = pk2(b[0], b[1]); z.u[3] = pk2(b[2], b[3]);
  return z.s;
}

// ============ Kernel 0: W fp32 -> bf16, reordered into 32-k panels ============
// Wb2 layout: [32 panels][192 rows][32 k] bf16; rows 0-63=Wq (pre-scaled by
// SCL2 -> scores arrive in log2 domain), 64-127=Wk, 128-191=Wv.
__global__ void wcvt_kernel(const float* __restrict__ Wq, const float* __restrict__ Wk,
                            const float* __restrict__ Wv, short* __restrict__ Wb2) {
  const int t   = blockIdx.x * 256 + threadIdx.x;  // 0..24575, 8 elems each
  const int row = t >> 7;
  const int k   = (t & 127) * 8;
  const float* src = (row < 64) ? (Wq + (size_t)row * EMB)
                   : (row < 128) ? (Wk + (size_t)(row - 64) * EMB)
                                 : (Wv + (size_t)(row - 128) * EMB);
  const float sc = (row < 64) ? SCL2 : 1.0f;
  float4v a = *(const float4v*)(src + k);
  float4v b = *(const float4v*)(src + k + 4);
#pragma unroll
  for (int i = 0; i < 4; ++i) { a[i] *= sc; b[i] *= sc; }
  *(short8*)(Wb2 + (((k >> 5) * 192 + row) << 5) + (k & 31)) = cvt8(a, b);
}

// ======================= Kernel 1: QKV projection GEMM =======================
// m97-style async GEMM: 512 blocks x 256 thr (2/CU), M-tile 32, BK=64.
// Both x (fp32) and W panels (bf16) staged via global_load_lds width=16 into
// double-buffered LDS; one barrier/step, next-stage DMA issued AFTER the
// barrier so it overlaps compute. (unchanged)
__global__ __launch_bounds__(256, 2) void qkv_kernel(
    const float* __restrict__ x, const short* __restrict__ Wb2,
    short* __restrict__ Qb, short* __restrict__ Kb, short* __restrict__ Vt) {
  __shared__ float As[2][2048];   // 2 x 8 KB  (32 rows x 64 k fp32, slot order)
  __shared__ short Bs[2][12288];  // 2 x 24 KB (2 panels x 192 x 32 bf16, identity)

  const int tid  = threadIdx.x;
  const int w    = tid >> 6;
  const int lane = tid & 63;
  const int ln   = lane & 15;
  const int quad = lane >> 4;
  const int m0   = blockIdx.x * 32;
  const int wr   = w & 1;
  const int wc   = w >> 1;

  const int tA0 = 2 * w, tA1 = 2 * w + 1;
  const float* xA0 = x + (size_t)(m0 + ((tA0 >> 2) << 4) + (lane >> 2)) * EMB
                       + ((tA0 & 3) * 4 + (lane & 3)) * 4;
  const float* xA1 = x + (size_t)(m0 + ((tA1 >> 2) << 4) + (lane >> 2)) * EMB
                       + ((tA1 & 3) * 4 + (lane & 3)) * 4;
  const short* wB = Wb2 + (size_t)(6 * w) * 512 + lane * 8;

#define STAGE(S, BUF) do {                                                      \
    __builtin_amdgcn_global_load_lds((AS1)(xA0 + (S) * 64),                     \
        (AS3)&As[BUF][tA0 * 256], 16, 0, 0);                                    \
    __builtin_amdgcn_global_load_lds((AS1)(xA1 + (S) * 64),                     \
        (AS3)&As[BUF][tA1 * 256], 16, 0, 0);                                    \
    _Pragma("unroll")                                                           \
    for (int j = 0; j < 6; ++j)                                                 \
      __builtin_amdgcn_global_load_lds((AS1)(wB + (size_t)(S) * 12288 + j * 512),\
          (AS3)&Bs[BUF][(6 * w + j) * 512], 16, 0, 0);                          \
  } while (0)

  const float4v zz = {0.f, 0.f, 0.f, 0.f};
  float4v acc[6] = {zz, zz, zz, zz, zz, zz};

  STAGE(0, 0);
  int buf = 0;
  for (int s = 0; s < 16; ++s) {
    __syncthreads();                       // drains this buf's DMA (vmcnt 0)
    if (s + 1 < 16) STAGE(s + 1, buf ^ 1); // overlaps with compute below
    short8 aF[2];
#pragma unroll
    for (int h = 0; h < 2; ++h) {
      const int ai = (wr * 4 + 2 * h + (quad >> 1)) * 256 + (ln * 4 + (quad & 1) * 2) * 4;
      const float4v lo = *(const float4v*)&As[buf][ai];
      const float4v hi = *(const float4v*)&As[buf][ai + 4];
      aF[h] = cvt8(lo, hi);
    }
#pragma unroll
    for (int f = 0; f < 6; ++f) {
      const int cf = wc * 6 + f;
      const short8 b0 = *(const short8*)&Bs[buf][(cf * 16 + ln) * 32 + quad * 8];
      const short8 b1 = *(const short8*)&Bs[buf][6144 + (cf * 16 + ln) * 32 + quad * 8];
      if (wc == 0 || f < 2) {
        acc[f] = MFMA16(aF[0], b0, acc[f]);
        acc[f] = MFMA16(aF[1], b1, acc[f]);
      } else {  // V frags: operand swap -> transposed output
        acc[f] = MFMA16(b0, aF[0], acc[f]);
        acc[f] = MFMA16(b1, aF[1], acc[f]);
      }
    }
    buf ^= 1;
  }
#undef STAGE

  const int b  = m0 >> 12;
  const int sb = m0 & (S_LEN - 1);
  if (wc == 0) {
#pragma unroll
    for (int f = 0; f < 6; ++f)
#pragma unroll
      for (int r = 0; r < 4; ++r) {
        const int row = m0 + wr * 16 + quad * 4 + r;
        if (f < 4) Qb[(size_t)row * DD + f * 16 + ln] = f2bf(acc[f][r]);
        else       Kb[(size_t)row * DD + (f - 4) * 16 + ln] = f2bf(acc[f][r]);
      }
  } else {
#pragma unroll
    for (int f = 0; f < 2; ++f)
#pragma unroll
      for (int r = 0; r < 4; ++r) {
        const int row = m0 + wr * 16 + quad * 4 + r;
        Kb[(size_t)row * DD + 32 + f * 16 + ln] = f2bf(acc[f][r]);
      }
#pragma unroll
    for (int f = 2; f < 6; ++f)
#pragma unroll
      for (int r = 0; r < 4; ++r) {
        const int d = (f - 2) * 16 + quad * 4 + r;
        Vt[((size_t)b * DD + d) * S_LEN + sb + wr * 16 + ln] = f2bf(acc[f][r]);
      }
  }
}

// ======================= Kernel 2: causal flash attention =======================
// Round 12: match the block quantum to HW register capacity.
// Round 4 post-mortem: per-wave total (96 VGPR + ~64 acc for s+o = ~160)
// caps HW at 12 waves/CU, so an 8-wave block can never co-reside with
// another (needs 16) -- block GRANULARITY wasted 4 wave-slots/CU. Fix:
// 4-wave (256-thread) blocks over 16-row bands, grid 1024 = 4 blocks/CU,
// entire grid resident at once. Per-wave regs also shrink (~100 total:
// aQ8 Kc16 Vc16 s16 o16 aP8 lp4 + addr) -> 4-5 waves/SIMD capacity.
// Balance: block g -> u=g&255, batch=g>>8, band=(batch&1)?255-u:u, so each
// CU's 4 blocks carry bands {u,255-u,u,255-u} = constant tile total (~130).
#define PSTRW 68

__global__ __launch_bounds__(256, 2) void attn_kernel(
    const short* __restrict__ Qb, const short* __restrict__ Kb,
    const short* __restrict__ Vt, float* __restrict__ out) {
  __shared__ float sbuf[4][16 * PSTRW];
  __shared__ float llds[4][16];

  const int tid  = threadIdx.x;
  const int w    = tid >> 6;       // 0..3
  const int lane = tid & 63;
  const int ln   = lane & 15;
  const int quad = lane >> 4;
  const int g    = blockIdx.x;
  const int u    = g & 255;
  const int b    = g >> 8;                       // batch 0..3
  const int band = (b & 1) ? (255 - u) : u;      // complementary per-CU pairing
  const short* Kbase = Kb + (size_t)b * S_LEN * DD;
  const short* Vbase = Vt + (size_t)b * DD * S_LEN;
  float* pw = &sbuf[w][0];
  const float4v zz = {0.f, 0.f, 0.f, 0.f};

  const int qb  = band * 16;
  const int qg0 = b * S_LEN + qb;

  short8 aQ[2];
#pragma unroll
  for (int h = 0; h < 2; ++h)
    aQ[h] = *(const short8*)(Qb + (size_t)(qg0 + ln) * DD + h * 32 + quad * 8);

  float4v o[4];
  float lp[4];
#pragma unroll
  for (int d = 0; d < 4; ++d) { o[d] = zz; lp[d] = 0.f; }

  const int T = (qb + 79) >> 6;   // tiles covering kv <= qb+15

  for (int it = w; it < T; it += 4) {
    const int kv0 = it * 64;
    // K for this tile (single-buffered; issued first so QK's wait is short)
    short8 Kc[4][2];
#pragma unroll
    for (int c = 0; c < 4; ++c)
#pragma unroll
      for (int h = 0; h < 2; ++h)
        Kc[c][h] = *(const short8*)(Kbase + (size_t)(kv0 + c * 16 + ln) * DD + h * 32 + quad * 8);
    // V issued second; stays in flight through QK^T + exp
    short8 Vc[4][2];
#pragma unroll
    for (int d = 0; d < 4; ++d)
#pragma unroll
      for (int h = 0; h < 2; ++h)
        Vc[d][h] = *(const short8*)(Vbase + (size_t)(d * 16 + ln) * S_LEN + kv0 + h * 32 + quad * 8);

    float4v s[4];
#pragma unroll
    for (int c = 0; c < 4; ++c) {
      s[c] = MFMA16(aQ[0], Kc[c][0], zz);
      s[c] = MFMA16(aQ[1], Kc[c][1], s[c]);
    }

    // P = exp2(S) (scores pre-scaled to log2 domain); single v_exp_f32 each.
    // Mask branch is wave-uniform: only the diagonal tile takes it.
    if ((kv0 + 63) > qb) {
#pragma unroll
      for (int c = 0; c < 4; ++c)
#pragma unroll
        for (int r = 0; r < 4; ++r) {
          float e = __builtin_amdgcn_exp2f(fminf(s[c][r], 60.0f));
          if (kv0 + c * 16 + ln > qb + quad * 4 + r) e = 0.f;
          s[c][r] = e;
        }
    } else {
#pragma unroll
      for (int c = 0; c < 4; ++c)
#pragma unroll
        for (int r = 0; r < 4; ++r)
          s[c][r] = __builtin_amdgcn_exp2f(fminf(s[c][r], 60.0f));
    }

#pragma unroll
    for (int r = 0; r < 4; ++r)
      lp[r] += s[0][r] + s[1][r] + s[2][r] + s[3][r];
#pragma unroll
    for (int c = 0; c < 4; ++c)
#pragma unroll
      for (int r = 0; r < 4; ++r)
        pw[(quad * 4 + r) * PSTRW + c * 16 + ln] = s[c][r];

    asm volatile("s_waitcnt lgkmcnt(0)" ::: "memory");
    short8 aP[2];
#pragma unroll
    for (int h = 0; h < 2; ++h) {
      const float4v lo = *(const float4v*)&pw[ln * PSTRW + h * 32 + quad * 8];
      const float4v hi = *(const float4v*)&pw[ln * PSTRW + h * 32 + quad * 8 + 4];
      aP[h] = cvt8(lo, hi);
    }
#pragma unroll
    for (int d = 0; d < 4; ++d) {
      o[d] = MFMA16(aP[0], Vc[d][0], o[d]);
      o[d] = MFMA16(aP[1], Vc[d][1], o[d]);
    }
  }

#pragma unroll
  for (int r = 0; r < 4; ++r) {
    float lr = lp[r];
    lr += __shfl_xor(lr, 1);
    lr += __shfl_xor(lr, 2);
    lr += __shfl_xor(lr, 4);
    lr += __shfl_xor(lr, 8);
    if (ln == 0) llds[w][quad * 4 + r] = lr;
#pragma unroll
    for (int d = 0; d < 4; ++d)
      pw[(quad * 4 + r) * 64 + d * 16 + ln] = o[d][r];
  }
  __syncthreads();

#pragma unroll
  for (int jx = 0; jx < 4; ++jx) {
    const int idx = tid + jx * 256;       // 16 rows x 64 cols = 1024
    const int row = idx >> 6, col = idx & 63;
    float sum = 0.f, lt = 0.f;
#pragma unroll
    for (int wi = 0; wi < 4; ++wi) {
      sum += sbuf[wi][row * 64 + col];
      lt  += llds[wi][row];
    }
    out[(size_t)(qg0 + row) * DD + col] = sum * __builtin_amdgcn_rcpf(lt);
  }
}

extern "C" void kernel_launch(void* const* d_in, const int* in_sizes, int n_in,
                              void* d_out, int out_size, void* d_ws, size_t ws_size,
                              hipStream_t stream) {
  const float* x  = (const float*)d_in[0];
  const float* Wq = (const float*)d_in[1];
  const float* Wk = (const float*)d_in[2];
  const float* Wv = (const float*)d_in[3];

  short* Qb  = (short*)d_ws;                       // 2 MB
  short* Kb  = Qb + (size_t)NROWS * DD;            // 2 MB
  short* Vt  = Kb + (size_t)NROWS * DD;            // 2 MB  [b][d][s]
  short* Wb2 = Vt + (size_t)NROWS * DD;            // 384 KB panels

  wcvt_kernel<<<dim3(96), dim3(256), 0, stream>>>(Wq, Wk, Wv, Wb2);
  qkv_kernel<<<dim3(NROWS / 32), dim3(256), 0, stream>>>(x, Wb2, Qb, Kb, Vt);
  attn_kernel<<<dim3(NBATCH * 256), dim3(256), 0, stream>>>(Qb, Kb, Vt, (float*)d_out);
}

// Round 6
// 159.753 us; speedup vs baseline: 1.1400x; 1.1400x over previous
//
#include <hip/hip_runtime.h>
#include <hip/hip_bf16.h>
#include <stdint.h>

typedef __attribute__((ext_vector_type(8))) short  short8;   // 8 bf16 (4 VGPR) MFMA A/B frag
typedef __attribute__((ext_vector_type(4))) short  short4v;
typedef __attribute__((ext_vector_type(4))) float  float4v;  // MFMA C/D frag

#define MFMA16(a, b, c) __builtin_amdgcn_mfma_f32_16x16x32_bf16((a), (b), (c), 0, 0, 0)

#define S_LEN  4096
#define NBATCH 4
#define EMB    1024
#define DD     64
#define NROWS  (NBATCH * S_LEN)  // 16384
#define SCL2   0.1803368801111204f  // (1/sqrt(64)) * log2(e), folded into Wq at wcvt

#define AS1 const __attribute__((address_space(1))) unsigned int*
#define AS3 __attribute__((address_space(3))) unsigned int*

static __device__ __forceinline__ short f2bf(float f) {
  uint32_t u = __float_as_uint(f);
  return (short)((u + 0x7FFFu + ((u >> 16) & 1u)) >> 16);
}
static __device__ __forceinline__ unsigned pk2(float a, float b) {
  union { __hip_bfloat162 h; unsigned u; } z;
  z.h = __float22bfloat162_rn(make_float2(a, b));
  return z.u;
}
static __device__ __forceinline__ short8 cvt8(float4v a, float4v b) {
  union { unsigned u[4]; short8 s; } z;
  z.u[0] = pk2(a[0], a[1]); z.u[1] = pk2(a[2], a[3]);
  z.u[2] = pk2(b[0], b[1]); z.u[3] = pk2(b[2], b[3]);
  return z.s;
}

// ============ Kernel 0: W fp32 -> bf16, reordered into 32-k panels ============
// Wb2 layout: [32 panels][192 rows][32 k] bf16; rows 0-63=Wq (pre-scaled by
// SCL2 -> scores arrive in log2 domain), 64-127=Wk, 128-191=Wv.
__global__ void wcvt_kernel(const float* __restrict__ Wq, const float* __restrict__ Wk,
                            const float* __restrict__ Wv, short* __restrict__ Wb2) {
  const int t   = blockIdx.x * 256 + threadIdx.x;  // 0..24575, 8 elems each
  const int row = t >> 7;
  const int k   = (t & 127) * 8;
  const float* src = (row < 64) ? (Wq + (size_t)row * EMB)
                   : (row < 128) ? (Wk + (size_t)(row - 64) * EMB)
                                 : (Wv + (size_t)(row - 128) * EMB);
  const float sc = (row < 64) ? SCL2 : 1.0f;
  float4v a = *(const float4v*)(src + k);
  float4v b = *(const float4v*)(src + k + 4);
#pragma unroll
  for (int i = 0; i < 4; ++i) { a[i] *= sc; b[i] *= sc; }
  *(short8*)(Wb2 + (((k >> 5) * 192 + row) << 5) + (k & 31)) = cvt8(a, b);
}

// ======================= Kernel 1: QKV projection GEMM =======================
// m97-style async GEMM: 512 blocks x 256 thr (2/CU), M-tile 32, BK=64.
// Both x (fp32) and W panels (bf16) staged via global_load_lds width=16 into
// double-buffered LDS; one barrier/step, next-stage DMA issued AFTER the
// barrier so it overlaps compute. (unchanged)
__global__ __launch_bounds__(256, 2) void qkv_kernel(
    const float* __restrict__ x, const short* __restrict__ Wb2,
    short* __restrict__ Qb, short* __restrict__ Kb, short* __restrict__ Vt) {
  __shared__ float As[2][2048];   // 2 x 8 KB  (32 rows x 64 k fp32, slot order)
  __shared__ short Bs[2][12288];  // 2 x 24 KB (2 panels x 192 x 32 bf16, identity)

  const int tid  = threadIdx.x;
  const int w    = tid >> 6;
  const int lane = tid & 63;
  const int ln   = lane & 15;
  const int quad = lane >> 4;
  const int m0   = blockIdx.x * 32;
  const int wr   = w & 1;
  const int wc   = w >> 1;

  const int tA0 = 2 * w, tA1 = 2 * w + 1;
  const float* xA0 = x + (size_t)(m0 + ((tA0 >> 2) << 4) + (lane >> 2)) * EMB
                       + ((tA0 & 3) * 4 + (lane & 3)) * 4;
  const float* xA1 = x + (size_t)(m0 + ((tA1 >> 2) << 4) + (lane >> 2)) * EMB
                       + ((tA1 & 3) * 4 + (lane & 3)) * 4;
  const short* wB = Wb2 + (size_t)(6 * w) * 512 + lane * 8;

#define STAGE(S, BUF) do {                                                      \
    __builtin_amdgcn_global_load_lds((AS1)(xA0 + (S) * 64),                     \
        (AS3)&As[BUF][tA0 * 256], 16, 0, 0);                                    \
    __builtin_amdgcn_global_load_lds((AS1)(xA1 + (S) * 64),                     \
        (AS3)&As[BUF][tA1 * 256], 16, 0, 0);                                    \
    _Pragma("unroll")                                                           \
    for (int j = 0; j < 6; ++j)                                                 \
      __builtin_amdgcn_global_load_lds((AS1)(wB + (size_t)(S) * 12288 + j * 512),\
          (AS3)&Bs[BUF][(6 * w + j) * 512], 16, 0, 0);                          \
  } while (0)

  const float4v zz = {0.f, 0.f, 0.f, 0.f};
  float4v acc[6] = {zz, zz, zz, zz, zz, zz};

  STAGE(0, 0);
  int buf = 0;
  for (int s = 0; s < 16; ++s) {
    __syncthreads();                       // drains this buf's DMA (vmcnt 0)
    if (s + 1 < 16) STAGE(s + 1, buf ^ 1); // overlaps with compute below
    short8 aF[2];
#pragma unroll
    for (int h = 0; h < 2; ++h) {
      const int ai = (wr * 4 + 2 * h + (quad >> 1)) * 256 + (ln * 4 + (quad & 1) * 2) * 4;
      const float4v lo = *(const float4v*)&As[buf][ai];
      const float4v hi = *(const float4v*)&As[buf][ai + 4];
      aF[h] = cvt8(lo, hi);
    }
#pragma unroll
    for (int f = 0; f < 6; ++f) {
      const int cf = wc * 6 + f;
      const short8 b0 = *(const short8*)&Bs[buf][(cf * 16 + ln) * 32 + quad * 8];
      const short8 b1 = *(const short8*)&Bs[buf][6144 + (cf * 16 + ln) * 32 + quad * 8];
      if (wc == 0 || f < 2) {
        acc[f] = MFMA16(aF[0], b0, acc[f]);
        acc[f] = MFMA16(aF[1], b1, acc[f]);
      } else {  // V frags: operand swap -> transposed output
        acc[f] = MFMA16(b0, aF[0], acc[f]);
        acc[f] = MFMA16(b1, aF[1], acc[f]);
      }
    }
    buf ^= 1;
  }
#undef STAGE

  const int b  = m0 >> 12;
  const int sb = m0 & (S_LEN - 1);
  if (wc == 0) {
#pragma unroll
    for (int f = 0; f < 6; ++f)
#pragma unroll
      for (int r = 0; r < 4; ++r) {
        const int row = m0 + wr * 16 + quad * 4 + r;
        if (f < 4) Qb[(size_t)row * DD + f * 16 + ln] = f2bf(acc[f][r]);
        else       Kb[(size_t)row * DD + (f - 4) * 16 + ln] = f2bf(acc[f][r]);
      }
  } else {
#pragma unroll
    for (int f = 0; f < 2; ++f)
#pragma unroll
      for (int r = 0; r < 4; ++r) {
        const int row = m0 + wr * 16 + quad * 4 + r;
        Kb[(size_t)row * DD + 32 + f * 16 + ln] = f2bf(acc[f][r]);
      }
#pragma unroll
    for (int f = 2; f < 6; ++f)
#pragma unroll
      for (int r = 0; r < 4; ++r) {
        const int d = (f - 2) * 16 + quad * 4 + r;
        Vt[((size_t)b * DD + d) * S_LEN + sb + wr * 16 + ln] = f2bf(acc[f][r]);
      }
  }
}

// ======================= Kernel 2: causal flash attention =======================
// Round 13: round-4 structure (32-row bands, 8-wave blocks, grid 512 -- the
// verified 41.4 us best) + K-prefetch software pipeline.
// Round 5 post-mortem: finer blocks double per-tile overhead (FETCH 5->17 MB,
// dur 65 us) -- occupancy via block granularity is a losing trade. Register
// model: ~160 total (96 arch + 64 acc) lands in the 129-256 occupancy bucket
// (waves/SIMD halve at 64/128/256) -> 2 waves/SIMD is FIXED for anything in
// that bucket. So spend the ~96 free regs on ILP instead: ping-pong K buffers
// (Ka/Kb2), next tile's K issued at the top of the current tile -> its L2
// latency (~200-400cy) hides under ~600cy of compute; steady-state vmcnt
// wait ~= 0. Unroll-by-2 with static buffer names (no v_mov copies, no
// runtime-indexed arrays -> no scratch). V stays single-buffered, issued
// right after QK so its latency hides under exp+LDS round-trip.
#define PSTRW 68

static __device__ __forceinline__ void tile_step(
    const short8 (&aQ)[2][2], const short8 (&Kc)[4][2],
    const short* __restrict__ Vbase, const int kv0, const int qb,
    const int ln, const int quad, float* __restrict__ pw,
    float4v (&o)[2][4], float (&lp)[2][4]) {
  const float4v zz = {0.f, 0.f, 0.f, 0.f};
  float4v s[2][4];
#pragma unroll
  for (int rfi = 0; rfi < 2; ++rfi)
#pragma unroll
    for (int c = 0; c < 4; ++c) {
      s[rfi][c] = MFMA16(aQ[rfi][0], Kc[c][0], zz);
      s[rfi][c] = MFMA16(aQ[rfi][1], Kc[c][1], s[rfi][c]);
    }
  // V issued after QK: its latency hides under exp + LDS round-trip below.
  short8 Vc[4][2];
#pragma unroll
  for (int d = 0; d < 4; ++d)
#pragma unroll
    for (int h = 0; h < 2; ++h)
      Vc[d][h] = *(const short8*)(Vbase + (size_t)(d * 16 + ln) * S_LEN + kv0 + h * 32 + quad * 8);

  // P = exp2(S) (scores pre-scaled to log2 domain); single v_exp_f32 each.
  // Mask branch is wave-uniform: only the diagonal tile takes it.
  if ((kv0 + 63) > qb) {
#pragma unroll
    for (int rfi = 0; rfi < 2; ++rfi)
#pragma unroll
      for (int c = 0; c < 4; ++c)
#pragma unroll
        for (int r = 0; r < 4; ++r) {
          float e = __builtin_amdgcn_exp2f(fminf(s[rfi][c][r], 60.0f));
          if (kv0 + c * 16 + ln > qb + rfi * 16 + quad * 4 + r) e = 0.f;
          s[rfi][c][r] = e;
        }
  } else {
#pragma unroll
    for (int rfi = 0; rfi < 2; ++rfi)
#pragma unroll
      for (int c = 0; c < 4; ++c)
#pragma unroll
        for (int r = 0; r < 4; ++r)
          s[rfi][c][r] = __builtin_amdgcn_exp2f(fminf(s[rfi][c][r], 60.0f));
  }

#pragma unroll
  for (int rfi = 0; rfi < 2; ++rfi) {
#pragma unroll
    for (int r = 0; r < 4; ++r)
      lp[rfi][r] += s[rfi][0][r] + s[rfi][1][r] + s[rfi][2][r] + s[rfi][3][r];
#pragma unroll
    for (int c = 0; c < 4; ++c)
#pragma unroll
      for (int r = 0; r < 4; ++r)
        pw[(rfi * 16 + quad * 4 + r) * PSTRW + c * 16 + ln] = s[rfi][c][r];
  }
  asm volatile("s_waitcnt lgkmcnt(0)" ::: "memory");
  short8 aP[2][2];
#pragma unroll
  for (int rfi = 0; rfi < 2; ++rfi)
#pragma unroll
    for (int h = 0; h < 2; ++h) {
      const float4v lo = *(const float4v*)&pw[(rfi * 16 + ln) * PSTRW + h * 32 + quad * 8];
      const float4v hi = *(const float4v*)&pw[(rfi * 16 + ln) * PSTRW + h * 32 + quad * 8 + 4];
      aP[rfi][h] = cvt8(lo, hi);
    }
#pragma unroll
  for (int rfi = 0; rfi < 2; ++rfi)
#pragma unroll
    for (int d = 0; d < 4; ++d) {
      o[rfi][d] = MFMA16(aP[rfi][0], Vc[d][0], o[rfi][d]);
      o[rfi][d] = MFMA16(aP[rfi][1], Vc[d][1], o[rfi][d]);
    }
}

__global__ __launch_bounds__(512, 2) void attn_kernel(
    const short* __restrict__ Qb, const short* __restrict__ Kb,
    const short* __restrict__ Vt, float* __restrict__ out) {
  __shared__ float sbuf[8][32 * PSTRW];
  __shared__ float llds[8][32];

  const int tid  = threadIdx.x;
  const int w    = tid >> 6;
  const int lane = tid & 63;
  const int ln   = lane & 15;
  const int quad = lane >> 4;
  const int g    = blockIdx.x;
  const int u    = g & 255;
  const int half = g >> 8;
  const int b    = u & 3;
  const int jj   = u >> 2;
  const int band = half ? (127 - jj) : jj;
  const short* Kbase = Kb + (size_t)b * S_LEN * DD;
  const short* Vbase = Vt + (size_t)b * DD * S_LEN;
  float* pw = &sbuf[w][0];
  const float4v zz = {0.f, 0.f, 0.f, 0.f};

  const int qb  = band * 32;
  const int qg0 = b * S_LEN + qb;

  short8 aQ[2][2];
#pragma unroll
  for (int rfi = 0; rfi < 2; ++rfi)
#pragma unroll
    for (int h = 0; h < 2; ++h)
      aQ[rfi][h] = *(const short8*)(Qb + (size_t)(qg0 + rfi * 16 + ln) * DD + h * 32 + quad * 8);

  float4v o[2][4];
  float lp[2][4];
#pragma unroll
  for (int rfi = 0; rfi < 2; ++rfi)
#pragma unroll
    for (int d = 0; d < 4; ++d) { o[rfi][d] = zz; lp[rfi][d] = 0.f; }

  const int T = (qb + 95) >> 6;

#define LOADK(DST, KV) do {                                                    \
    _Pragma("unroll")                                                          \
    for (int c = 0; c < 4; ++c)                                                \
      _Pragma("unroll")                                                        \
      for (int h = 0; h < 2; ++h)                                              \
        DST[c][h] = *(const short8*)(Kbase + (size_t)((KV) + c * 16 + ln) * DD + h * 32 + quad * 8); \
  } while (0)

  short8 Ka[4][2], Kb2[4][2];
  int it = w;
  if (it < T) LOADK(Ka, it * 64);
  while (it < T) {
    const int it1 = it + 8;
    LOADK(Kb2, (it1 < T) ? it1 * 64 : 0);        // prefetch (dummy tail ok)
    tile_step(aQ, Ka, Vbase, it * 64, qb, ln, quad, pw, o, lp);
    if (it1 >= T) break;
    const int it2 = it1 + 8;
    LOADK(Ka, (it2 < T) ? it2 * 64 : 0);         // prefetch (dummy tail ok)
    tile_step(aQ, Kb2, Vbase, it1 * 64, qb, ln, quad, pw, o, lp);
    it = it2;
  }
#undef LOADK

#pragma unroll
  for (int rfi = 0; rfi < 2; ++rfi)
#pragma unroll
    for (int r = 0; r < 4; ++r) {
      float lr = lp[rfi][r];
      lr += __shfl_xor(lr, 1);
      lr += __shfl_xor(lr, 2);
      lr += __shfl_xor(lr, 4);
      lr += __shfl_xor(lr, 8);
      if (ln == 0) llds[w][rfi * 16 + quad * 4 + r] = lr;
#pragma unroll
      for (int d = 0; d < 4; ++d)
        pw[(rfi * 16 + quad * 4 + r) * 64 + d * 16 + ln] = o[rfi][d][r];
    }
  __syncthreads();

#pragma unroll
  for (int jx = 0; jx < 4; ++jx) {
    const int idx = tid + jx * 512;
    const int row = idx >> 6, col = idx & 63;
    float sum = 0.f, lt = 0.f;
#pragma unroll
    for (int wi = 0; wi < 8; ++wi) {
      sum += sbuf[wi][row * 64 + col];
      lt  += llds[wi][row];
    }
    out[(size_t)(qg0 + row) * DD + col] = sum * __builtin_amdgcn_rcpf(lt);
  }
}

extern "C" void kernel_launch(void* const* d_in, const int* in_sizes, int n_in,
                              void* d_out, int out_size, void* d_ws, size_t ws_size,
                              hipStream_t stream) {
  const float* x  = (const float*)d_in[0];
  const float* Wq = (const float*)d_in[1];
  const float* Wk = (const float*)d_in[2];
  const float* Wv = (const float*)d_in[3];

  short* Qb  = (short*)d_ws;                       // 2 MB
  short* Kb  = Qb + (size_t)NROWS * DD;            // 2 MB
  short* Vt  = Kb + (size_t)NROWS * DD;            // 2 MB  [b][d][s]
  short* Wb2 = Vt + (size_t)NROWS * DD;            // 384 KB panels

  wcvt_kernel<<<dim3(96), dim3(256), 0, stream>>>(Wq, Wk, Wv, Wb2);
  qkv_kernel<<<dim3(NROWS / 32), dim3(256), 0, stream>>>(x, Wb2, Qb, Kb, Vt);
  attn_kernel<<<dim3(NBATCH * 128), dim3(512), 0, stream>>>(Qb, Kb, Vt, (float*)d_out);
}

// Round 7
// 155.394 us; speedup vs baseline: 1.1720x; 1.0281x over previous
//
#include <hip/hip_runtime.h>
#include <hip/hip_bf16.h>
#include <stdint.h>

typedef __attribute__((ext_vector_type(8))) short  short8;   // 8 bf16 (4 VGPR) MFMA A/B frag
typedef __attribute__((ext_vector_type(4))) short  short4v;
typedef __attribute__((ext_vector_type(4))) float  float4v;  // 16x16 MFMA C/D frag
typedef __attribute__((ext_vector_type(16))) float f32x16;   // 32x32 MFMA C/D frag
typedef __attribute__((ext_vector_type(2))) unsigned int uint2v;

#define MFMA16(a, b, c) __builtin_amdgcn_mfma_f32_16x16x32_bf16((a), (b), (c), 0, 0, 0)
#define MFMA32(a, b, c) __builtin_amdgcn_mfma_f32_32x32x16_bf16((a), (b), (c), 0, 0, 0)

#define S_LEN  4096
#define NBATCH 4
#define EMB    1024
#define DD     64
#define NROWS  (NBATCH * S_LEN)  // 16384
#define SCL2   0.1803368801111204f  // (1/sqrt(64)) * log2(e), folded into Wq at wcvt

#define AS1 const __attribute__((address_space(1))) unsigned int*
#define AS3 __attribute__((address_space(3))) unsigned int*

static __device__ __forceinline__ short f2bf(float f) {
  uint32_t u = __float_as_uint(f);
  return (short)((u + 0x7FFFu + ((u >> 16) & 1u)) >> 16);
}
static __device__ __forceinline__ unsigned pk2(float a, float b) {
  union { __hip_bfloat162 h; unsigned u; } z;
  z.h = __float22bfloat162_rn(make_float2(a, b));
  return z.u;
}
static __device__ __forceinline__ short8 cvt8(float4v a, float4v b) {
  union { unsigned u[4]; short8 s; } z;
  z.u[0] = pk2(a[0], a[1]); z.u[1] = pk2(a[2], a[3]);
  z.u[2] = pk2(b[0], b[1]); z.u[3] = pk2(b[2], b[3]);
  return z.s;
}

// ============ Kernel 0: W fp32 -> bf16, reordered into 32-k panels ============
// Wb2 layout: [32 panels][192 rows][32 k] bf16; rows 0-63=Wq (pre-scaled by
// SCL2 -> scores arrive in log2 domain), 64-127=Wk, 128-191=Wv.
__global__ void wcvt_kernel(const float* __restrict__ Wq, const float* __restrict__ Wk,
                            const float* __restrict__ Wv, short* __restrict__ Wb2) {
  const int t   = blockIdx.x * 256 + threadIdx.x;  // 0..24575, 8 elems each
  const int row = t >> 7;
  const int k   = (t & 127) * 8;
  const float* src = (row < 64) ? (Wq + (size_t)row * EMB)
                   : (row < 128) ? (Wk + (size_t)(row - 64) * EMB)
                                 : (Wv + (size_t)(row - 128) * EMB);
  const float sc = (row < 64) ? SCL2 : 1.0f;
  float4v a = *(const float4v*)(src + k);
  float4v b = *(const float4v*)(src + k + 4);
#pragma unroll
  for (int i = 0; i < 4; ++i) { a[i] *= sc; b[i] *= sc; }
  *(short8*)(Wb2 + (((k >> 5) * 192 + row) << 5) + (k & 31)) = cvt8(a, b);
}

// ======================= Kernel 1: QKV projection GEMM =======================
// m97-style async GEMM: 512 blocks x 256 thr (2/CU), M-tile 32, BK=64.
// Both x (fp32) and W panels (bf16) staged via global_load_lds width=16 into
// double-buffered LDS; one barrier/step, next-stage DMA issued AFTER the
// barrier so it overlaps compute. (unchanged)
__global__ __launch_bounds__(256, 2) void qkv_kernel(
    const float* __restrict__ x, const short* __restrict__ Wb2,
    short* __restrict__ Qb, short* __restrict__ Kb, short* __restrict__ Vt) {
  __shared__ float As[2][2048];   // 2 x 8 KB  (32 rows x 64 k fp32, slot order)
  __shared__ short Bs[2][12288];  // 2 x 24 KB (2 panels x 192 x 32 bf16, identity)

  const int tid  = threadIdx.x;
  const int w    = tid >> 6;
  const int lane = tid & 63;
  const int ln   = lane & 15;
  const int quad = lane >> 4;
  const int m0   = blockIdx.x * 32;
  const int wr   = w & 1;
  const int wc   = w >> 1;

  const int tA0 = 2 * w, tA1 = 2 * w + 1;
  const float* xA0 = x + (size_t)(m0 + ((tA0 >> 2) << 4) + (lane >> 2)) * EMB
                       + ((tA0 & 3) * 4 + (lane & 3)) * 4;
  const float* xA1 = x + (size_t)(m0 + ((tA1 >> 2) << 4) + (lane >> 2)) * EMB
                       + ((tA1 & 3) * 4 + (lane & 3)) * 4;
  const short* wB = Wb2 + (size_t)(6 * w) * 512 + lane * 8;

#define STAGE(S, BUF) do {                                                      \
    __builtin_amdgcn_global_load_lds((AS1)(xA0 + (S) * 64),                     \
        (AS3)&As[BUF][tA0 * 256], 16, 0, 0);                                    \
    __builtin_amdgcn_global_load_lds((AS1)(xA1 + (S) * 64),                     \
        (AS3)&As[BUF][tA1 * 256], 16, 0, 0);                                    \
    _Pragma("unroll")                                                           \
    for (int j = 0; j < 6; ++j)                                                 \
      __builtin_amdgcn_global_load_lds((AS1)(wB + (size_t)(S) * 12288 + j * 512),\
          (AS3)&Bs[BUF][(6 * w + j) * 512], 16, 0, 0);                          \
  } while (0)

  const float4v zz = {0.f, 0.f, 0.f, 0.f};
  float4v acc[6] = {zz, zz, zz, zz, zz, zz};

  STAGE(0, 0);
  int buf = 0;
  for (int s = 0; s < 16; ++s) {
    __syncthreads();                       // drains this buf's DMA (vmcnt 0)
    if (s + 1 < 16) STAGE(s + 1, buf ^ 1); // overlaps with compute below
    short8 aF[2];
#pragma unroll
    for (int h = 0; h < 2; ++h) {
      const int ai = (wr * 4 + 2 * h + (quad >> 1)) * 256 + (ln * 4 + (quad & 1) * 2) * 4;
      const float4v lo = *(const float4v*)&As[buf][ai];
      const float4v hi = *(const float4v*)&As[buf][ai + 4];
      aF[h] = cvt8(lo, hi);
    }
#pragma unroll
    for (int f = 0; f < 6; ++f) {
      const int cf = wc * 6 + f;
      const short8 b0 = *(const short8*)&Bs[buf][(cf * 16 + ln) * 32 + quad * 8];
      const short8 b1 = *(const short8*)&Bs[buf][6144 + (cf * 16 + ln) * 32 + quad * 8];
      if (wc == 0 || f < 2) {
        acc[f] = MFMA16(aF[0], b0, acc[f]);
        acc[f] = MFMA16(aF[1], b1, acc[f]);
      } else {  // V frags: operand swap -> transposed output
        acc[f] = MFMA16(b0, aF[0], acc[f]);
        acc[f] = MFMA16(b1, aF[1], acc[f]);
      }
    }
    buf ^= 1;
  }
#undef STAGE

  const int b  = m0 >> 12;
  const int sb = m0 & (S_LEN - 1);
  if (wc == 0) {
#pragma unroll
    for (int f = 0; f < 6; ++f)
#pragma unroll
      for (int r = 0; r < 4; ++r) {
        const int row = m0 + wr * 16 + quad * 4 + r;
        if (f < 4) Qb[(size_t)row * DD + f * 16 + ln] = f2bf(acc[f][r]);
        else       Kb[(size_t)row * DD + (f - 4) * 16 + ln] = f2bf(acc[f][r]);
      }
  } else {
#pragma unroll
    for (int f = 0; f < 2; ++f)
#pragma unroll
      for (int r = 0; r < 4; ++r) {
        const int row = m0 + wr * 16 + quad * 4 + r;
        Kb[(size_t)row * DD + 32 + f * 16 + ln] = f2bf(acc[f][r]);
      }
#pragma unroll
    for (int f = 2; f < 6; ++f)
#pragma unroll
      for (int r = 0; r < 4; ++r) {
        const int d = (f - 2) * 16 + quad * 4 + r;
        Vt[((size_t)b * DD + d) * S_LEN + sb + wr * 16 + ln] = f2bf(acc[f][r]);
      }
  }
}

// ======================= Kernel 2: causal flash attention =======================
// Round 14: 32x32x16 swapped-QK^T, softmax + P-transpose fully IN-REGISTER.
// Round 6 falsified the memory-latency theory (K-prefetch neutral) -> the
// in-tile serial chain (exp -> 32 ds_write -> lgkm wait -> 8 ds_read -> cvt)
// was the bottleneck. New structure per 64-kv tile (per wave):
//   S^T = mfma32(K, Q): lane holds P[kv-slots][q = lane&31]
//     (C/D: row=(e&3)+8*(e>>2)+4*hi, col=lane&31 -- m74/m101-verified)
//   exp2 + causal mask + row-sum: all lane-local (q fixed per lane)
//   P -> bf16 A-frags: 16x v_cvt_pk_bf16_f32 + 8x permlane32_swap:
//     swap(pk(s0,s1), pk(s4,s5)) -> word0 & word2 of the kv0-15 A-frag:
//     lanes<32 keep kv{0,1}/{4,5}; lanes>=32 receive kv{8,9}/{12,13}  == A
//     layout row=lane&31(q), k=(lane>>5)*8+j. Words 1/3 from pk(s2,s3)x
//     pk(s6,s7); kv16-31 frag from s8..s15 likewise.
//   O^T += mfma32(P_frag, V^T_frag): lane holds O[q-slots][d = lane&31(+32)]
// Zero LDS / zero lgkm waits in the loop (LDS only in the per-band epilogue).
// Regs ~111 arch + 64 acc = same 129-256 bucket as before: occupancy is
// unchanged by design; the win is pure serial-chain shortening.
__global__ __launch_bounds__(512, 2) void attn_kernel(
    const short* __restrict__ Qb, const short* __restrict__ Kb,
    const short* __restrict__ Vt, float* __restrict__ out) {
  __shared__ float sbuf[8][2048];   // 8 waves x 32q x 64d f32 partial O
  __shared__ float llds[8][32];     // 8 waves x 32q partial row-sums

  const int tid  = threadIdx.x;
  const int w    = tid >> 6;
  const int lane = tid & 63;
  const int l31  = lane & 31;
  const int hi   = lane >> 5;
  const int g    = blockIdx.x;
  const int u    = g & 255;
  const int half = g >> 8;
  const int b    = u & 3;
  const int jj   = u >> 2;
  const int band = half ? (127 - jj) : jj;
  const short* Kbase = Kb + (size_t)b * S_LEN * DD;
  const short* Vbase = Vt + (size_t)b * DD * S_LEN;

  const int qb    = band * 32;
  const int qg0   = b * S_LEN + qb;
  const int qglob = qb + l31;     // this lane's q row (global within batch)

  // Q as B-fragments: lane holds Q[qb + l31][dk = dkc*16 + hi*8 + 0..7]
  short8 q8[4];
#pragma unroll
  for (int dk = 0; dk < 4; ++dk)
    q8[dk] = *(const short8*)(Qb + (size_t)(qg0 + l31) * DD + dk * 16 + hi * 8);

  f32x16 o0, o1;
  f32x16 zz16;
#pragma unroll
  for (int e = 0; e < 16; ++e) { o0[e] = 0.f; o1[e] = 0.f; zz16[e] = 0.f; }
  float lp = 0.f;

  const int T = (qb + 95) >> 6;

  for (int it = w; it < T; it += 8) {
    const int kv0 = it * 64;
    // K as A-frags: lane holds K[kv0 + c*32 + l31][dk = dkc*16 + hi*8 + 0..7]
    short8 kf[2][4];
#pragma unroll
    for (int c = 0; c < 2; ++c)
#pragma unroll
      for (int dk = 0; dk < 4; ++dk)
        kf[c][dk] = *(const short8*)(Kbase + (size_t)(kv0 + c * 32 + l31) * DD + dk * 16 + hi * 8);
    // V^T as B-frags: lane holds V^T[df*32 + l31][kv = kc*16 + hi*8 + 0..7]
    short8 vf[2][4];
#pragma unroll
    for (int df = 0; df < 2; ++df)
#pragma unroll
      for (int kc = 0; kc < 4; ++kc)
        vf[df][kc] = *(const short8*)(Vbase + (size_t)(df * 32 + l31) * S_LEN + kv0 + kc * 16 + hi * 8);

    // S^T[kv][q]: two 32-kv chunks, K-dim (head dim 64) chained over 4 mfmas
    f32x16 s0 = MFMA32(kf[0][0], q8[0], zz16);
    f32x16 s1 = MFMA32(kf[1][0], q8[0], zz16);
#pragma unroll
    for (int dk = 1; dk < 4; ++dk) {
      s0 = MFMA32(kf[0][dk], q8[dk], s0);
      s1 = MFMA32(kf[1][dk], q8[dk], s1);
    }

    // P = exp2(S) (log2 domain); causal mask only on the diagonal tile
    // (wave-uniform branch). kv slot of element e: (e&3)+8*(e>>2)+4*hi.
    if (kv0 + 63 > qb) {
#pragma unroll
      for (int e = 0; e < 16; ++e) {
        const int kvl = (e & 3) + 8 * (e >> 2) + 4 * hi;
        float e0 = __builtin_amdgcn_exp2f(fminf(s0[e], 60.0f));
        if (kv0 + kvl > qglob) e0 = 0.f;
        float e1 = __builtin_amdgcn_exp2f(fminf(s1[e], 60.0f));
        if (kv0 + 32 + kvl > qglob) e1 = 0.f;
        s0[e] = e0; s1[e] = e1;
        lp += e0 + e1;
      }
    } else {
#pragma unroll
      for (int e = 0; e < 16; ++e) {
        float e0 = __builtin_amdgcn_exp2f(fminf(s0[e], 60.0f));
        float e1 = __builtin_amdgcn_exp2f(fminf(s1[e], 60.0f));
        s0[e] = e0; s1[e] = e1;
        lp += e0 + e1;
      }
    }

    // ---- in-register P->bf16 A-frags + PV, per 32-kv chunk ----
#define PACK_PV(S, V00, V01, V10, V11) do {                                     \
    unsigned ua, ub, uc, ud, ue, uf2, ug, uh;                                   \
    asm("v_cvt_pk_bf16_f32 %0, %1, %2" : "=v"(ua) : "v"((S)[0]),  "v"((S)[1])); \
    asm("v_cvt_pk_bf16_f32 %0, %1, %2" : "=v"(ub) : "v"((S)[2]),  "v"((S)[3])); \
    asm("v_cvt_pk_bf16_f32 %0, %1, %2" : "=v"(uc) : "v"((S)[4]),  "v"((S)[5])); \
    asm("v_cvt_pk_bf16_f32 %0, %1, %2" : "=v"(ud) : "v"((S)[6]),  "v"((S)[7])); \
    asm("v_cvt_pk_bf16_f32 %0, %1, %2" : "=v"(ue) : "v"((S)[8]),  "v"((S)[9])); \
    asm("v_cvt_pk_bf16_f32 %0, %1, %2" : "=v"(uf2): "v"((S)[10]), "v"((S)[11]));\
    asm("v_cvt_pk_bf16_f32 %0, %1, %2" : "=v"(ug) : "v"((S)[12]), "v"((S)[13]));\
    asm("v_cvt_pk_bf16_f32 %0, %1, %2" : "=v"(uh) : "v"((S)[14]), "v"((S)[15]));\
    uint2v r0 = __builtin_amdgcn_permlane32_swap(ua, uc, false, false);         \
    uint2v r1 = __builtin_amdgcn_permlane32_swap(ub, ud, false, false);         \
    uint2v r2 = __builtin_amdgcn_permlane32_swap(ue, ug, false, false);         \
    uint2v r3 = __builtin_amdgcn_permlane32_swap(uf2, uh, false, false);        \
    union { unsigned uu[4]; short8 s8; } p0, p1;                                \
    p0.uu[0] = r0[0]; p0.uu[1] = r1[0]; p0.uu[2] = r0[1]; p0.uu[3] = r1[1];     \
    p1.uu[0] = r2[0]; p1.uu[1] = r3[0]; p1.uu[2] = r2[1]; p1.uu[3] = r3[1];     \
    o0 = MFMA32(p0.s8, (V00), o0);                                              \
    o0 = MFMA32(p1.s8, (V01), o0);                                              \
    o1 = MFMA32(p0.s8, (V10), o1);                                              \
    o1 = MFMA32(p1.s8, (V11), o1);                                              \
  } while (0)

    PACK_PV(s0, vf[0][0], vf[0][1], vf[1][0], vf[1][1]);
    PACK_PV(s1, vf[0][2], vf[0][3], vf[1][2], vf[1][3]);
#undef PACK_PV
  }

  // ---- epilogue: combine the 8 waves' disjoint-kv partials via LDS ----
  lp += __shfl_xor(lp, 32);   // complementary kv-slots live in lane^32
  float* pw = &sbuf[w][0];
#pragma unroll
  for (int e = 0; e < 16; ++e) {
    const int ql = (e & 3) + 8 * (e >> 2) + 4 * hi;   // q slot of element e
    pw[ql * 64 + l31]      = o0[e];
    pw[ql * 64 + 32 + l31] = o1[e];
  }
  if (hi == 0) llds[w][l31] = lp;
  __syncthreads();

#pragma unroll
  for (int jx = 0; jx < 4; ++jx) {
    const int idx = tid + jx * 512;     // 32q x 64d = 2048
    const int row = idx >> 6, col = idx & 63;
    float sum = 0.f, lt = 0.f;
#pragma unroll
    for (int wi = 0; wi < 8; ++wi) {
      sum += sbuf[wi][row * 64 + col];
      lt  += llds[wi][row];
    }
    out[(size_t)(qg0 + row) * DD + col] = sum * __builtin_amdgcn_rcpf(lt);
  }
}

extern "C" void kernel_launch(void* const* d_in, const int* in_sizes, int n_in,
                              void* d_out, int out_size, void* d_ws, size_t ws_size,
                              hipStream_t stream) {
  const float* x  = (const float*)d_in[0];
  const float* Wq = (const float*)d_in[1];
  const float* Wk = (const float*)d_in[2];
  const float* Wv = (const float*)d_in[3];

  short* Qb  = (short*)d_ws;                       // 2 MB
  short* Kb  = Qb + (size_t)NROWS * DD;            // 2 MB
  short* Vt  = Kb + (size_t)NROWS * DD;            // 2 MB  [b][d][s]
  short* Wb2 = Vt + (size_t)NROWS * DD;            // 384 KB panels

  wcvt_kernel<<<dim3(96), dim3(256), 0, stream>>>(Wq, Wk, Wv, Wb2);
  qkv_kernel<<<dim3(NROWS / 32), dim3(256), 0, stream>>>(x, Wb2, Qb, Kb, Vt);
  attn_kernel<<<dim3(NBATCH * 128), dim3(512), 0, stream>>>(Qb, Kb, Vt, (float*)d_out);
}

// Round 8
// 153.892 us; speedup vs baseline: 1.1835x; 1.0098x over previous
//
#include <hip/hip_runtime.h>
#include <hip/hip_bf16.h>
#include <stdint.h>

typedef __attribute__((ext_vector_type(8))) short  short8;   // 8 bf16 (4 VGPR) MFMA A/B frag
typedef __attribute__((ext_vector_type(4))) short  short4v;
typedef __attribute__((ext_vector_type(4))) float  float4v;  // 16x16 MFMA C/D frag
typedef __attribute__((ext_vector_type(16))) float f32x16;   // 32x32 MFMA C/D frag
typedef __attribute__((ext_vector_type(2))) unsigned int uint2v;

#define MFMA16(a, b, c) __builtin_amdgcn_mfma_f32_16x16x32_bf16((a), (b), (c), 0, 0, 0)
#define MFMA32(a, b, c) __builtin_amdgcn_mfma_f32_32x32x16_bf16((a), (b), (c), 0, 0, 0)

#define S_LEN  4096
#define NBATCH 4
#define EMB    1024
#define DD     64
#define NROWS  (NBATCH * S_LEN)  // 16384
#define SCL2   0.1803368801111204f  // (1/sqrt(64)) * log2(e), folded into Wq at wcvt

#define AS1 const __attribute__((address_space(1))) unsigned int*
#define AS3 __attribute__((address_space(3))) unsigned int*

static __device__ __forceinline__ short f2bf(float f) {
  uint32_t u = __float_as_uint(f);
  return (short)((u + 0x7FFFu + ((u >> 16) & 1u)) >> 16);
}
static __device__ __forceinline__ unsigned pk2(float a, float b) {
  union { __hip_bfloat162 h; unsigned u; } z;
  z.h = __float22bfloat162_rn(make_float2(a, b));
  return z.u;
}
static __device__ __forceinline__ short8 cvt8(float4v a, float4v b) {
  union { unsigned u[4]; short8 s; } z;
  z.u[0] = pk2(a[0], a[1]); z.u[1] = pk2(a[2], a[3]);
  z.u[2] = pk2(b[0], b[1]); z.u[3] = pk2(b[2], b[3]);
  return z.s;
}

// ============ Kernel 0: W fp32 -> bf16, reordered into 32-k panels ============
// Wb2 layout: [32 panels][192 rows][32 k] bf16; rows 0-63=Wq (pre-scaled by
// SCL2 -> scores arrive in log2 domain), 64-127=Wk, 128-191=Wv.
__global__ void wcvt_kernel(const float* __restrict__ Wq, const float* __restrict__ Wk,
                            const float* __restrict__ Wv, short* __restrict__ Wb2) {
  const int t   = blockIdx.x * 256 + threadIdx.x;  // 0..24575, 8 elems each
  const int row = t >> 7;
  const int k   = (t & 127) * 8;
  const float* src = (row < 64) ? (Wq + (size_t)row * EMB)
                   : (row < 128) ? (Wk + (size_t)(row - 64) * EMB)
                                 : (Wv + (size_t)(row - 128) * EMB);
  const float sc = (row < 64) ? SCL2 : 1.0f;
  float4v a = *(const float4v*)(src + k);
  float4v b = *(const float4v*)(src + k + 4);
#pragma unroll
  for (int i = 0; i < 4; ++i) { a[i] *= sc; b[i] *= sc; }
  *(short8*)(Wb2 + (((k >> 5) * 192 + row) << 5) + (k & 31)) = cvt8(a, b);
}

// ======================= Kernel 1: QKV projection GEMM =======================
// m97-style async GEMM: 512 blocks x 256 thr (2/CU), M-tile 32, BK=64.
// Both x (fp32) and W panels (bf16) staged via global_load_lds width=16 into
// double-buffered LDS; one barrier/step, next-stage DMA issued AFTER the
// barrier so it overlaps compute. (unchanged)
__global__ __launch_bounds__(256, 2) void qkv_kernel(
    const float* __restrict__ x, const short* __restrict__ Wb2,
    short* __restrict__ Qb, short* __restrict__ Kb, short* __restrict__ Vt) {
  __shared__ float As[2][2048];   // 2 x 8 KB  (32 rows x 64 k fp32, slot order)
  __shared__ short Bs[2][12288];  // 2 x 24 KB (2 panels x 192 x 32 bf16, identity)

  const int tid  = threadIdx.x;
  const int w    = tid >> 6;
  const int lane = tid & 63;
  const int ln   = lane & 15;
  const int quad = lane >> 4;
  const int m0   = blockIdx.x * 32;
  const int wr   = w & 1;
  const int wc   = w >> 1;

  const int tA0 = 2 * w, tA1 = 2 * w + 1;
  const float* xA0 = x + (size_t)(m0 + ((tA0 >> 2) << 4) + (lane >> 2)) * EMB
                       + ((tA0 & 3) * 4 + (lane & 3)) * 4;
  const float* xA1 = x + (size_t)(m0 + ((tA1 >> 2) << 4) + (lane >> 2)) * EMB
                       + ((tA1 & 3) * 4 + (lane & 3)) * 4;
  const short* wB = Wb2 + (size_t)(6 * w) * 512 + lane * 8;

#define STAGE(S, BUF) do {                                                      \
    __builtin_amdgcn_global_load_lds((AS1)(xA0 + (S) * 64),                     \
        (AS3)&As[BUF][tA0 * 256], 16, 0, 0);                                    \
    __builtin_amdgcn_global_load_lds((AS1)(xA1 + (S) * 64),                     \
        (AS3)&As[BUF][tA1 * 256], 16, 0, 0);                                    \
    _Pragma("unroll")                                                           \
    for (int j = 0; j < 6; ++j)                                                 \
      __builtin_amdgcn_global_load_lds((AS1)(wB + (size_t)(S) * 12288 + j * 512),\
          (AS3)&Bs[BUF][(6 * w + j) * 512], 16, 0, 0);                          \
  } while (0)

  const float4v zz = {0.f, 0.f, 0.f, 0.f};
  float4v acc[6] = {zz, zz, zz, zz, zz, zz};

  STAGE(0, 0);
  int buf = 0;
  for (int s = 0; s < 16; ++s) {
    __syncthreads();                       // drains this buf's DMA (vmcnt 0)
    if (s + 1 < 16) STAGE(s + 1, buf ^ 1); // overlaps with compute below
    short8 aF[2];
#pragma unroll
    for (int h = 0; h < 2; ++h) {
      const int ai = (wr * 4 + 2 * h + (quad >> 1)) * 256 + (ln * 4 + (quad & 1) * 2) * 4;
      const float4v lo = *(const float4v*)&As[buf][ai];
      const float4v hi = *(const float4v*)&As[buf][ai + 4];
      aF[h] = cvt8(lo, hi);
    }
#pragma unroll
    for (int f = 0; f < 6; ++f) {
      const int cf = wc * 6 + f;
      const short8 b0 = *(const short8*)&Bs[buf][(cf * 16 + ln) * 32 + quad * 8];
      const short8 b1 = *(const short8*)&Bs[buf][6144 + (cf * 16 + ln) * 32 + quad * 8];
      if (wc == 0 || f < 2) {
        acc[f] = MFMA16(aF[0], b0, acc[f]);
        acc[f] = MFMA16(aF[1], b1, acc[f]);
      } else {  // V frags: operand swap -> transposed output
        acc[f] = MFMA16(b0, aF[0], acc[f]);
        acc[f] = MFMA16(b1, aF[1], acc[f]);
      }
    }
    buf ^= 1;
  }
#undef STAGE

  const int b  = m0 >> 12;
  const int sb = m0 & (S_LEN - 1);
  if (wc == 0) {
#pragma unroll
    for (int f = 0; f < 6; ++f)
#pragma unroll
      for (int r = 0; r < 4; ++r) {
        const int row = m0 + wr * 16 + quad * 4 + r;
        if (f < 4) Qb[(size_t)row * DD + f * 16 + ln] = f2bf(acc[f][r]);
        else       Kb[(size_t)row * DD + (f - 4) * 16 + ln] = f2bf(acc[f][r]);
      }
  } else {
#pragma unroll
    for (int f = 0; f < 2; ++f)
#pragma unroll
      for (int r = 0; r < 4; ++r) {
        const int row = m0 + wr * 16 + quad * 4 + r;
        Kb[(size_t)row * DD + 32 + f * 16 + ln] = f2bf(acc[f][r]);
      }
#pragma unroll
    for (int f = 2; f < 6; ++f)
#pragma unroll
      for (int r = 0; r < 4; ++r) {
        const int d = (f - 2) * 16 + quad * 4 + r;
        Vt[((size_t)b * DD + d) * S_LEN + sb + wr * 16 + ln] = f2bf(acc[f][r]);
      }
  }
}

// ======================= Kernel 2: causal flash attention =======================
// Round 15: 32-kv tiles + declared 128-reg budget -> 2 blocks/CU.
// Register model (validated R1-R7): rocprof VGPR_Count EXCLUDES the AGPR
// (accumulator) side of gfx950's unified file; occupancy follows arch+acc.
// R7's 64-kv tiles: ~108 arch + 64 acc (s0,s1,o0,o1) = 172 > 128 -> stuck at
// 1 block/CU (19% occ). This round: 32-kv tiles halve the per-tile state --
// acc 48 (s 16 + o 32), arch ~70-80 (q8 16, kf 16, vf 16, pack temps, addr).
// __launch_bounds__(512,4) declares the 128 budget the structure actually
// fits (unlike R1/R2 where the need was 160+ and the declaration forced a
// 40-reg spill). Result: 16 waves/CU, 2 independent blocks overlap each
// other's QK->exp->pack->PV chains. Work per kv unchanged (same load rate,
// same MFMA FLOP); only loop overhead doubles. PACK_PV permlane mapping is
// hardware-verified as of R7 (passed).
__global__ __launch_bounds__(512, 4) void attn_kernel(
    const short* __restrict__ Qb, const short* __restrict__ Kb,
    const short* __restrict__ Vt, float* __restrict__ out) {
  __shared__ float sbuf[8][2048];   // 8 waves x 32q x 64d f32 partial O (64 KB)
  __shared__ float llds[8][32];     // 8 waves x 32q partial row-sums

  const int tid  = threadIdx.x;
  const int w    = tid >> 6;
  const int lane = tid & 63;
  const int l31  = lane & 31;
  const int hi   = lane >> 5;
  const int g    = blockIdx.x;
  const int u    = g & 255;
  const int half = g >> 8;
  const int b    = u & 3;
  const int jj   = u >> 2;
  const int band = half ? (127 - jj) : jj;
  const short* Kbase = Kb + (size_t)b * S_LEN * DD;
  const short* Vbase = Vt + (size_t)b * DD * S_LEN;

  const int qb    = band * 32;
  const int qg0   = b * S_LEN + qb;
  const int qglob = qb + l31;     // this lane's q row (global within batch)

  // Q as B-fragments: lane holds Q[qb + l31][dk = dkc*16 + hi*8 + 0..7]
  short8 q8[4];
#pragma unroll
  for (int dk = 0; dk < 4; ++dk)
    q8[dk] = *(const short8*)(Qb + (size_t)(qg0 + l31) * DD + dk * 16 + hi * 8);

  f32x16 o0, o1;
  f32x16 zz16;
#pragma unroll
  for (int e = 0; e < 16; ++e) { o0[e] = 0.f; o1[e] = 0.f; zz16[e] = 0.f; }
  float lp = 0.f;

  const int T32 = band + 1;   // 32-kv tiles covering kv <= qb+31

  for (int it = w; it < T32; it += 8) {
    const int kv0 = it * 32;
    // K as A-frag: lane holds K[kv0 + l31][dk*16 + hi*8 + 0..7]
    short8 kf[4];
#pragma unroll
    for (int dk = 0; dk < 4; ++dk)
      kf[dk] = *(const short8*)(Kbase + (size_t)(kv0 + l31) * DD + dk * 16 + hi * 8);
    // V^T as B-frags: lane holds V^T[df*32 + l31][kv = kv0 + kc*16 + hi*8 + 0..7]
    short8 vf[2][2];
#pragma unroll
    for (int df = 0; df < 2; ++df)
#pragma unroll
      for (int kc = 0; kc < 2; ++kc)
        vf[df][kc] = *(const short8*)(Vbase + (size_t)(df * 32 + l31) * S_LEN + kv0 + kc * 16 + hi * 8);

    // S^T[kv][q]: head dim 64 chained over 4 mfma32
    f32x16 s = MFMA32(kf[0], q8[0], zz16);
#pragma unroll
    for (int dk = 1; dk < 4; ++dk)
      s = MFMA32(kf[dk], q8[dk], s);

    // P = exp2(S) (log2 domain); causal mask only on the diagonal tile
    // (wave-uniform: it == band). kv slot of element e: (e&3)+8*(e>>2)+4*hi.
    if (it == band) {
#pragma unroll
      for (int e = 0; e < 16; ++e) {
        const int kvl = (e & 3) + 8 * (e >> 2) + 4 * hi;
        float e0 = __builtin_amdgcn_exp2f(fminf(s[e], 60.0f));
        if (kv0 + kvl > qglob) e0 = 0.f;
        s[e] = e0;
        lp += e0;
      }
    } else {
#pragma unroll
      for (int e = 0; e < 16; ++e) {
        float e0 = __builtin_amdgcn_exp2f(fminf(s[e], 60.0f));
        s[e] = e0;
        lp += e0;
      }
    }

    // ---- in-register P->bf16 A-frags + PV (mapping HW-verified in R7) ----
    {
      unsigned ua, ub, uc, ud, ue, uf2, ug, uh;
      asm("v_cvt_pk_bf16_f32 %0, %1, %2" : "=v"(ua) : "v"(s[0]),  "v"(s[1]));
      asm("v_cvt_pk_bf16_f32 %0, %1, %2" : "=v"(ub) : "v"(s[2]),  "v"(s[3]));
      asm("v_cvt_pk_bf16_f32 %0, %1, %2" : "=v"(uc) : "v"(s[4]),  "v"(s[5]));
      asm("v_cvt_pk_bf16_f32 %0, %1, %2" : "=v"(ud) : "v"(s[6]),  "v"(s[7]));
      asm("v_cvt_pk_bf16_f32 %0, %1, %2" : "=v"(ue) : "v"(s[8]),  "v"(s[9]));
      asm("v_cvt_pk_bf16_f32 %0, %1, %2" : "=v"(uf2): "v"(s[10]), "v"(s[11]));
      asm("v_cvt_pk_bf16_f32 %0, %1, %2" : "=v"(ug) : "v"(s[12]), "v"(s[13]));
      asm("v_cvt_pk_bf16_f32 %0, %1, %2" : "=v"(uh) : "v"(s[14]), "v"(s[15]));
      uint2v r0 = __builtin_amdgcn_permlane32_swap(ua, uc, false, false);
      uint2v r1 = __builtin_amdgcn_permlane32_swap(ub, ud, false, false);
      uint2v r2 = __builtin_amdgcn_permlane32_swap(ue, ug, false, false);
      uint2v r3 = __builtin_amdgcn_permlane32_swap(uf2, uh, false, false);
      union { unsigned uu[4]; short8 s8; } p0, p1;
      p0.uu[0] = r0[0]; p0.uu[1] = r1[0]; p0.uu[2] = r0[1]; p0.uu[3] = r1[1];
      p1.uu[0] = r2[0]; p1.uu[1] = r3[0]; p1.uu[2] = r2[1]; p1.uu[3] = r3[1];
      o0 = MFMA32(p0.s8, vf[0][0], o0);
      o0 = MFMA32(p1.s8, vf[0][1], o0);
      o1 = MFMA32(p0.s8, vf[1][0], o1);
      o1 = MFMA32(p1.s8, vf[1][1], o1);
    }
  }

  // ---- epilogue: combine the 8 waves' disjoint-kv partials via LDS ----
  lp += __shfl_xor(lp, 32);   // complementary kv-slots live in lane^32
  float* pw = &sbuf[w][0];
#pragma unroll
  for (int e = 0; e < 16; ++e) {
    const int ql = (e & 3) + 8 * (e >> 2) + 4 * hi;   // q slot of element e
    pw[ql * 64 + l31]      = o0[e];
    pw[ql * 64 + 32 + l31] = o1[e];
  }
  if (hi == 0) llds[w][l31] = lp;
  __syncthreads();

#pragma unroll
  for (int jx = 0; jx < 4; ++jx) {
    const int idx = tid + jx * 512;     // 32q x 64d = 2048
    const int row = idx >> 6, col = idx & 63;
    float sum = 0.f, lt = 0.f;
#pragma unroll
    for (int wi = 0; wi < 8; ++wi) {
      sum += sbuf[wi][row * 64 + col];
      lt  += llds[wi][row];
    }
    out[(size_t)(qg0 + row) * DD + col] = sum * __builtin_amdgcn_rcpf(lt);
  }
}

extern "C" void kernel_launch(void* const* d_in, const int* in_sizes, int n_in,
                              void* d_out, int out_size, void* d_ws, size_t ws_size,
                              hipStream_t stream) {
  const float* x  = (const float*)d_in[0];
  const float* Wq = (const float*)d_in[1];
  const float* Wk = (const float*)d_in[2];
  const float* Wv = (const float*)d_in[3];

  short* Qb  = (short*)d_ws;                       // 2 MB
  short* Kb  = Qb + (size_t)NROWS * DD;            // 2 MB
  short* Vt  = Kb + (size_t)NROWS * DD;            // 2 MB  [b][d][s]
  short* Wb2 = Vt + (size_t)NROWS * DD;            // 384 KB panels

  wcvt_kernel<<<dim3(96), dim3(256), 0, stream>>>(Wq, Wk, Wv, Wb2);
  qkv_kernel<<<dim3(NROWS / 32), dim3(256), 0, stream>>>(x, Wb2, Qb, Kb, Vt);
  attn_kernel<<<dim3(NBATCH * 128), dim3(512), 0, stream>>>(Qb, Kb, Vt, (float*)d_out);
}